// Round 10
// baseline (239.662 us; speedup 1.0000x reference)
//
#include <hip/hip_runtime.h>
#include <hip/hip_bf16.h>

#define DIM   1024
#define BATCH 8192
#define KV    16

typedef __attribute__((ext_vector_type(4))) float f32x4;
typedef __attribute__((ext_vector_type(8))) short short8;

static __device__ __forceinline__ unsigned short f2bf(float x) {
  return __builtin_bit_cast(unsigned short, __float2bfloat16(x));
}
static __device__ __forceinline__ float bf2f(unsigned short x) {
  return __bfloat162float(__builtin_bit_cast(__hip_bfloat16, x));
}
static __device__ __forceinline__ float dot4(f32x4 a, f32x4 b) {
  return a.x * b.x + a.y * b.y + a.z * b.z + a.w * b.w;
}

static __device__ __forceinline__ void gl_lds16(const unsigned short* g, unsigned short* l) {
  __builtin_amdgcn_global_load_lds(
      (const __attribute__((address_space(1))) void*)g,
      (__attribute__((address_space(3))) void*)l, 16, 0, 0);
}

// ---------------- kernel 1: Wq,Wk f32 -> transposed bf16 ----------------
__global__ __launch_bounds__(256) void transpose_w(const float* __restrict__ Wq,
                                                   const float* __restrict__ Wk,
                                                   unsigned short* __restrict__ WqT,
                                                   unsigned short* __restrict__ WkT) {
  __shared__ float tile[32][33];
  const float* src = blockIdx.z ? Wk : Wq;
  unsigned short* dst = blockIdx.z ? WkT : WqT;
  int tx = threadIdx.x & 31, ty = threadIdx.x >> 5;
  int x = blockIdx.x * 32 + tx;
  int y0 = blockIdx.y * 32;
  #pragma unroll
  for (int i = ty; i < 32; i += 8)
    tile[i][tx] = src[(size_t)(y0 + i) * DIM + x];
  __syncthreads();
  int x2 = blockIdx.y * 32 + tx;
  int y2 = blockIdx.x * 32;
  #pragma unroll
  for (int i = ty; i < 32; i += 8)
    dst[(size_t)(y2 + i) * DIM + x2] = f2bf(tile[tx][i]);
}

// ---------------- kernel 2: Mt = WkT x WqT^T, 64x64 tiles (256 blocks) ----------------
__global__ __launch_bounds__(256) void gemm_nt64(const unsigned short* __restrict__ A,
                                                 const unsigned short* __restrict__ B,
                                                 unsigned short* __restrict__ C,
                                                 int N, int K) {
  __shared__ __align__(16) unsigned short As[64 * 32];
  __shared__ __align__(16) unsigned short Bs[64 * 32];
  const int tid = threadIdx.x;
  const int lane = tid & 63;
  const int wave = tid >> 6;
  const int wr = wave >> 1, wc = wave & 1;
  const size_t bm = (size_t)blockIdx.x * 64;
  const size_t bn = (size_t)blockIdx.y * 64;

  f32x4 acc[2][2];
  #pragma unroll
  for (int m = 0; m < 2; ++m)
    #pragma unroll
    for (int n = 0; n < 2; ++n)
      acc[m][n] = (f32x4){0.f, 0.f, 0.f, 0.f};

  const int r0 = tid >> 2;
  const int cc = (tid & 3) * 8;
  const int kg = lane >> 4;
  const int rowf = lane & 15;

  for (int kt = 0; kt < K; kt += 32) {
    gl_lds16(A + (bm + r0) * K + kt + cc, As + tid * 8);
    gl_lds16(B + (bn + r0) * K + kt + cc, Bs + tid * 8);
    __syncthreads();
    short8 af[2], bfr[2];
    #pragma unroll
    for (int m = 0; m < 2; ++m)
      af[m] = *(const short8*)(As + ((wr * 32 + m * 16 + rowf) * 32 + kg * 8));
    #pragma unroll
    for (int n = 0; n < 2; ++n)
      bfr[n] = *(const short8*)(Bs + ((wc * 32 + n * 16 + rowf) * 32 + kg * 8));
    #pragma unroll
    for (int m = 0; m < 2; ++m)
      #pragma unroll
      for (int n = 0; n < 2; ++n)
        acc[m][n] = __builtin_amdgcn_mfma_f32_16x16x32_bf16(af[m], bfr[n], acc[m][n], 0, 0, 0);
    __syncthreads();
  }

  const int rq = (lane >> 4) * 4;
  const int colf = lane & 15;
  #pragma unroll
  for (int m = 0; m < 2; ++m)
    #pragma unroll
    for (int n = 0; n < 2; ++n)
      #pragma unroll
      for (int i = 0; i < 4; ++i)
        C[(bm + wr * 32 + m * 16 + rq + i) * N + bn + wc * 32 + n * 16 + colf] =
            f2bf(acc[m][n][i]);
}

// ---------------- kernel 3: u = query(f32) x Mt^T, 128x128, BK=32, 8 waves ----------
__global__ __launch_bounds__(512) void gemm_u(const float* __restrict__ Af,
                                              const unsigned short* __restrict__ B,
                                              unsigned short* __restrict__ C,
                                              int ntN, int ldc) {
  __shared__ __align__(16) unsigned short As[128 * 32];   // 8 KB
  __shared__ __align__(16) unsigned short Bs[128 * 32];   // 8 KB

  const int cpx = gridDim.x >> 3;          // XCD swizzle (512 % 8 == 0)
  const int wg = (blockIdx.x & 7) * cpx + (blockIdx.x >> 3);
  const size_t bm = (size_t)(wg / ntN) * 128;
  const size_t bn = (size_t)(wg % ntN) * 128;

  const int tid = threadIdx.x;
  const int lane = tid & 63;
  const int wave = tid >> 6;               // 0..7
  const int wr = wave >> 2, wc = wave & 3; // 2 x 4 wave grid

  f32x4 acc[4][2];
  #pragma unroll
  for (int m = 0; m < 4; ++m)
    #pragma unroll
    for (int n = 0; n < 2; ++n)
      acc[m][n] = (f32x4){0.f, 0.f, 0.f, 0.f};

  const int kg = lane >> 4;
  const int rowf = lane & 15;
  const int br0 = tid >> 2;
  const int bcc = (tid & 3) * 8;
  const int ar0 = tid >> 3;
  const int ak = (tid & 7) * 4;

  f32x4 pref[2];
  pref[0] = *(const f32x4*)(Af + (bm + ar0) * DIM + ak);
  pref[1] = *(const f32x4*)(Af + (bm + 64 + ar0) * DIM + ak);

  for (int kt = 0; kt < DIM; kt += 32) {
    gl_lds16(B + (bn + br0) * DIM + kt + bcc, Bs + tid * 8);
    {
      ushort4 o0, o1;
      o0.x = f2bf(pref[0].x); o0.y = f2bf(pref[0].y);
      o0.z = f2bf(pref[0].z); o0.w = f2bf(pref[0].w);
      o1.x = f2bf(pref[1].x); o1.y = f2bf(pref[1].y);
      o1.z = f2bf(pref[1].z); o1.w = f2bf(pref[1].w);
      *(ushort4*)(As + ar0 * 32 + ak) = o0;
      *(ushort4*)(As + (64 + ar0) * 32 + ak) = o1;
    }
    __syncthreads();
    if (kt + 32 < DIM) {
      pref[0] = *(const f32x4*)(Af + (bm + ar0) * DIM + kt + 32 + ak);
      pref[1] = *(const f32x4*)(Af + (bm + 64 + ar0) * DIM + kt + 32 + ak);
    }
    short8 af[4], bfr[2];
    #pragma unroll
    for (int m = 0; m < 4; ++m)
      af[m] = *(const short8*)(As + ((wr * 64 + m * 16 + rowf) * 32 + kg * 8));
    #pragma unroll
    for (int n = 0; n < 2; ++n)
      bfr[n] = *(const short8*)(Bs + ((wc * 32 + n * 16 + rowf) * 32 + kg * 8));
    #pragma unroll
    for (int m = 0; m < 4; ++m)
      #pragma unroll
      for (int n = 0; n < 2; ++n)
        acc[m][n] = __builtin_amdgcn_mfma_f32_16x16x32_bf16(af[m], bfr[n], acc[m][n], 0, 0, 0);
    __syncthreads();
  }

  const int rq = (lane >> 4) * 4;
  const int colf = lane & 15;
  #pragma unroll
  for (int m = 0; m < 4; ++m)
    #pragma unroll
    for (int n = 0; n < 2; ++n)
      #pragma unroll
      for (int i = 0; i < 4; ++i) {
        size_t row = bm + wr * 64 + m * 16 + rq + i;
        size_t col = bn + wc * 32 + n * 16 + colf;
        C[row * (size_t)ldc + col] = f2bf(acc[m][n][i]);
      }
}

// ---------------- kernel 4: fused attention epilogue (8192 blocks, 16 waves/CU) -------
// u bf16 strided in d_out; q f32. V split: rows 0-7 prefetched (32 VGPR), rows 8-15
// loaded after softmax -> lower VGPR, occupancy 12 -> 16+ waves/CU for the K/V stream.
__global__ __launch_bounds__(256, 4) void epilogue(const float* __restrict__ query,
                                                   const float* __restrict__ key,
                                                   const float* __restrict__ value,
                                                   const float* __restrict__ Wa,
                                                   const float* __restrict__ ba,
                                                   const unsigned short* __restrict__ u,
                                                   float* __restrict__ out) {
  const int b = blockIdx.x;
  const int tid = threadIdx.x;
  const int lane = tid & 63, wave = tid >> 6;
  const f32x4* k4 = (const f32x4*)(key + (size_t)b * KV * DIM);
  const f32x4* v4 = (const f32x4*)(value + (size_t)b * KV * DIM);

  f32x4 qv = ((const f32x4*)(query + (size_t)b * DIM))[tid];
  ushort4 ub = ((const ushort4*)(u + (size_t)b * 2048))[tid];
  f32x4 uv;
  uv.x = bf2f(ub.x); uv.y = bf2f(ub.y); uv.z = bf2f(ub.z); uv.w = bf2f(ub.w);
  f32x4 wv = ((const f32x4*)Wa)[tid];

  float s[17];
  s[0] = dot4(qv, uv);
  float ad = dot4(qv, wv);
  #pragma unroll
  for (int j = 1; j <= 16; ++j) {
    f32x4 kv = __builtin_nontemporal_load(k4 + (j - 1) * 256 + tid);
    s[j] = dot4(uv, kv);
  }

  // prefetch only V rows 0..7 before the reduction chains (half the V VGPR cost)
  f32x4 vv[8];
  #pragma unroll
  for (int j = 0; j < 8; ++j)
    vv[j] = __builtin_nontemporal_load(v4 + j * 256 + tid);

  #pragma unroll
  for (int m = 32; m >= 1; m >>= 1) {
    #pragma unroll
    for (int j = 0; j < 17; ++j) s[j] += __shfl_xor(s[j], m);
    ad += __shfl_xor(ad, m);
  }
  __shared__ float red[4][18];
  if (lane == 0) {
    #pragma unroll
    for (int j = 0; j < 17; ++j) red[wave][j] = s[j];
    red[wave][17] = ad;
  }
  __syncthreads();

  float wt[17];
  float mx = -1e30f;
  #pragma unroll
  for (int j = 0; j < 17; ++j) {
    float t = (red[0][j] + red[1][j] + red[2][j] + red[3][j]) * 0.03125f;
    wt[j] = t;
    mx = fmaxf(mx, t);
  }
  float den = 0.f;
  #pragma unroll
  for (int j = 0; j < 17; ++j) {
    wt[j] = expf(wt[j] - mx);
    den += wt[j];
  }
  float adt = red[0][17] + red[1][17] + red[2][17] + red[3][17] + ba[0];
  float alpha = 1.0f / (1.0f + expf(-adt));
  float am = alpha / den;

  f32x4 acc = qv * wt[0];
  #pragma unroll
  for (int j = 1; j <= 8; ++j) acc += vv[j - 1] * wt[j];
  // second half of V loaded now; latency covered by other waves (16 waves/CU)
  #pragma unroll
  for (int j = 9; j <= 16; ++j) {
    f32x4 v2 = __builtin_nontemporal_load(v4 + (j - 1) * 256 + tid);
    acc += v2 * wt[j];
  }
  f32x4 t = qv + acc * am;

  float ssp = dot4(t, t);
  #pragma unroll
  for (int m = 32; m >= 1; m >>= 1) ssp += __shfl_xor(ssp, m);
  __shared__ float red2[4];
  if (lane == 0) red2[wave] = ssp;
  __syncthreads();
  float nrm = sqrtf(red2[0] + red2[1] + red2[2] + red2[3]);
  float inv = 1.0f / fmaxf(nrm, 1e-12f);

  __builtin_nontemporal_store(t * inv, (f32x4*)(out + (size_t)b * DIM) + tid);
}

// ---------------- launcher ----------------
extern "C" void kernel_launch(void* const* d_in, const int* in_sizes, int n_in,
                              void* d_out, int out_size, void* d_ws, size_t ws_size,
                              hipStream_t stream) {
  const float* query = (const float*)d_in[0];
  const float* key   = (const float*)d_in[1];
  const float* value = (const float*)d_in[2];
  const float* Wq    = (const float*)d_in[3];
  const float* Wk    = (const float*)d_in[4];
  const float* Wa    = (const float*)d_in[5];
  const float* ba    = (const float*)d_in[6];

  unsigned short* WqT = (unsigned short*)d_ws;              // 2 MiB
  unsigned short* WkT = WqT + (size_t)DIM * DIM;            // 2 MiB
  unsigned short* Mt  = WkT + (size_t)DIM * DIM;            // 2 MiB
  unsigned short* ubf = (unsigned short*)d_out;             // strided bf16 u inside d_out

  transpose_w<<<dim3(32, 32, 2), 256, 0, stream>>>(Wq, Wk, WqT, WkT);
  gemm_nt64<<<dim3(16, 16), 256, 0, stream>>>(WkT, WqT, Mt, DIM, DIM);
  gemm_u<<<512, 512, 0, stream>>>(query, Mt, ubf, DIM / 128, 2048);
  epilogue<<<BATCH, 256, 0, stream>>>(query, key, value, Wa, ba, ubf, (float*)d_out);
}

// Round 11
// 235.511 us; speedup vs baseline: 1.0176x; 1.0176x over previous
//
#include <hip/hip_runtime.h>
#include <hip/hip_bf16.h>

#define DIM   1024
#define BATCH 8192
#define KV    16

typedef __attribute__((ext_vector_type(4))) float f32x4;
typedef __attribute__((ext_vector_type(8))) short short8;

static __device__ __forceinline__ unsigned short f2bf(float x) {
  return __builtin_bit_cast(unsigned short, __float2bfloat16(x));
}
static __device__ __forceinline__ float bf2f(unsigned short x) {
  return __bfloat162float(__builtin_bit_cast(__hip_bfloat16, x));
}
static __device__ __forceinline__ float dot4(f32x4 a, f32x4 b) {
  return a.x * b.x + a.y * b.y + a.z * b.z + a.w * b.w;
}

static __device__ __forceinline__ void gl_lds16(const unsigned short* g, unsigned short* l) {
  __builtin_amdgcn_global_load_lds(
      (const __attribute__((address_space(1))) void*)g,
      (__attribute__((address_space(3))) void*)l, 16, 0, 0);
}

// ---------------- kernel 1: Wq,Wk f32 -> transposed bf16 ----------------
__global__ __launch_bounds__(256) void transpose_w(const float* __restrict__ Wq,
                                                   const float* __restrict__ Wk,
                                                   unsigned short* __restrict__ WqT,
                                                   unsigned short* __restrict__ WkT) {
  __shared__ float tile[32][33];
  const float* src = blockIdx.z ? Wk : Wq;
  unsigned short* dst = blockIdx.z ? WkT : WqT;
  int tx = threadIdx.x & 31, ty = threadIdx.x >> 5;
  int x = blockIdx.x * 32 + tx;
  int y0 = blockIdx.y * 32;
  #pragma unroll
  for (int i = ty; i < 32; i += 8)
    tile[i][tx] = src[(size_t)(y0 + i) * DIM + x];
  __syncthreads();
  int x2 = blockIdx.y * 32 + tx;
  int y2 = blockIdx.x * 32;
  #pragma unroll
  for (int i = ty; i < 32; i += 8)
    dst[(size_t)(y2 + i) * DIM + x2] = f2bf(tile[tx][i]);
}

// ---------------- kernel 2: Mt = WkT x WqT^T, 64x64 tiles, in-block K-split ----------
// 512 threads = 8 waves. Waves 0-3 accumulate K=[0,512), waves 4-7 K=[512,1024)
// (independent LDS staging per half, aligned barrier counts: 16 serial steps, not 32).
// Halves combined through a stride-65 padded f32 LDS tile (conflict-free), half 0 writes C.
__global__ __launch_bounds__(512) void gemm_nt64ks(const unsigned short* __restrict__ A,
                                                   const unsigned short* __restrict__ B,
                                                   unsigned short* __restrict__ C,
                                                   int N, int K) {
  __shared__ __align__(16) unsigned short As[2][64 * 32];
  __shared__ __align__(16) unsigned short Bs[2][64 * 32];
  __shared__ float Cred[64 * 65];
  const int tid = threadIdx.x;       // 0..511
  const int half = tid >> 8;         // 0 | 1
  const int htid = tid & 255;
  const int lane = tid & 63;
  const int wave4 = (tid >> 6) & 3;  // wave index within half
  const int wr = wave4 >> 1, wc = wave4 & 1;
  const size_t bm = (size_t)blockIdx.x * 64;
  const size_t bn = (size_t)blockIdx.y * 64;

  f32x4 acc[2][2];
  #pragma unroll
  for (int m = 0; m < 2; ++m)
    #pragma unroll
    for (int n = 0; n < 2; ++n)
      acc[m][n] = (f32x4){0.f, 0.f, 0.f, 0.f};

  const int r0 = htid >> 2;
  const int cc = (htid & 3) * 8;
  const int kg = lane >> 4;
  const int rowf = lane & 15;
  const int kbase = half * (K / 2);

  for (int k32 = 0; k32 < K / 64; ++k32) {
    const int kt = kbase + k32 * 32;
    gl_lds16(A + (bm + r0) * K + kt + cc, As[half] + htid * 8);
    gl_lds16(B + (bn + r0) * K + kt + cc, Bs[half] + htid * 8);
    __syncthreads();
    short8 af[2], bfr[2];
    #pragma unroll
    for (int m = 0; m < 2; ++m)
      af[m] = *(const short8*)(As[half] + ((wr * 32 + m * 16 + rowf) * 32 + kg * 8));
    #pragma unroll
    for (int n = 0; n < 2; ++n)
      bfr[n] = *(const short8*)(Bs[half] + ((wc * 32 + n * 16 + rowf) * 32 + kg * 8));
    #pragma unroll
    for (int m = 0; m < 2; ++m)
      #pragma unroll
      for (int n = 0; n < 2; ++n)
        acc[m][n] = __builtin_amdgcn_mfma_f32_16x16x32_bf16(af[m], bfr[n], acc[m][n], 0, 0, 0);
    __syncthreads();
  }

  const int rq = (lane >> 4) * 4;
  const int colf = lane & 15;
  // half 1 deposits its accumulators; half 0 adds and writes C
  if (half == 1) {
    #pragma unroll
    for (int m = 0; m < 2; ++m)
      #pragma unroll
      for (int n = 0; n < 2; ++n)
        #pragma unroll
        for (int i = 0; i < 4; ++i)
          Cred[(wr * 32 + m * 16 + rq + i) * 65 + wc * 32 + n * 16 + colf] = acc[m][n][i];
  }
  __syncthreads();
  if (half == 0) {
    #pragma unroll
    for (int m = 0; m < 2; ++m)
      #pragma unroll
      for (int n = 0; n < 2; ++n)
        #pragma unroll
        for (int i = 0; i < 4; ++i) {
          int row = wr * 32 + m * 16 + rq + i;
          int col = wc * 32 + n * 16 + colf;
          float v = acc[m][n][i] + Cred[row * 65 + col];
          C[(bm + row) * N + bn + col] = f2bf(v);
        }
  }
}

// ---------------- kernel 3: u = query(f32) x Mt^T, 128x128, BK=32, 8 waves ----------
__global__ __launch_bounds__(512) void gemm_u(const float* __restrict__ Af,
                                              const unsigned short* __restrict__ B,
                                              unsigned short* __restrict__ C,
                                              int ntN, int ldc) {
  __shared__ __align__(16) unsigned short As[128 * 32];   // 8 KB
  __shared__ __align__(16) unsigned short Bs[128 * 32];   // 8 KB

  const int cpx = gridDim.x >> 3;          // XCD swizzle (512 % 8 == 0)
  const int wg = (blockIdx.x & 7) * cpx + (blockIdx.x >> 3);
  const size_t bm = (size_t)(wg / ntN) * 128;
  const size_t bn = (size_t)(wg % ntN) * 128;

  const int tid = threadIdx.x;
  const int lane = tid & 63;
  const int wave = tid >> 6;               // 0..7
  const int wr = wave >> 2, wc = wave & 3; // 2 x 4 wave grid

  f32x4 acc[4][2];
  #pragma unroll
  for (int m = 0; m < 4; ++m)
    #pragma unroll
    for (int n = 0; n < 2; ++n)
      acc[m][n] = (f32x4){0.f, 0.f, 0.f, 0.f};

  const int kg = lane >> 4;
  const int rowf = lane & 15;
  const int br0 = tid >> 2;
  const int bcc = (tid & 3) * 8;
  const int ar0 = tid >> 3;
  const int ak = (tid & 7) * 4;

  f32x4 pref[2];
  pref[0] = *(const f32x4*)(Af + (bm + ar0) * DIM + ak);
  pref[1] = *(const f32x4*)(Af + (bm + 64 + ar0) * DIM + ak);

  for (int kt = 0; kt < DIM; kt += 32) {
    gl_lds16(B + (bn + br0) * DIM + kt + bcc, Bs + tid * 8);
    {
      ushort4 o0, o1;
      o0.x = f2bf(pref[0].x); o0.y = f2bf(pref[0].y);
      o0.z = f2bf(pref[0].z); o0.w = f2bf(pref[0].w);
      o1.x = f2bf(pref[1].x); o1.y = f2bf(pref[1].y);
      o1.z = f2bf(pref[1].z); o1.w = f2bf(pref[1].w);
      *(ushort4*)(As + ar0 * 32 + ak) = o0;
      *(ushort4*)(As + (64 + ar0) * 32 + ak) = o1;
    }
    __syncthreads();
    if (kt + 32 < DIM) {
      pref[0] = *(const f32x4*)(Af + (bm + ar0) * DIM + kt + 32 + ak);
      pref[1] = *(const f32x4*)(Af + (bm + 64 + ar0) * DIM + kt + 32 + ak);
    }
    short8 af[4], bfr[2];
    #pragma unroll
    for (int m = 0; m < 4; ++m)
      af[m] = *(const short8*)(As + ((wr * 64 + m * 16 + rowf) * 32 + kg * 8));
    #pragma unroll
    for (int n = 0; n < 2; ++n)
      bfr[n] = *(const short8*)(Bs + ((wc * 32 + n * 16 + rowf) * 32 + kg * 8));
    #pragma unroll
    for (int m = 0; m < 4; ++m)
      #pragma unroll
      for (int n = 0; n < 2; ++n)
        acc[m][n] = __builtin_amdgcn_mfma_f32_16x16x32_bf16(af[m], bfr[n], acc[m][n], 0, 0, 0);
    __syncthreads();
  }

  const int rq = (lane >> 4) * 4;
  const int colf = lane & 15;
  #pragma unroll
  for (int m = 0; m < 4; ++m)
    #pragma unroll
    for (int n = 0; n < 2; ++n)
      #pragma unroll
      for (int i = 0; i < 4; ++i) {
        size_t row = bm + wr * 64 + m * 16 + rq + i;
        size_t col = bn + wc * 32 + n * 16 + colf;
        C[row * (size_t)ldc + col] = f2bf(acc[m][n][i]);
      }
}

// ---------------- kernel 4: fused attention epilogue (8192 blocks) ----------------
// u bf16 strided in d_out (row b at element b*2048); q read as f32 (exact residual).
__global__ __launch_bounds__(256) void epilogue(const float* __restrict__ query,
                                                const float* __restrict__ key,
                                                const float* __restrict__ value,
                                                const float* __restrict__ Wa,
                                                const float* __restrict__ ba,
                                                const unsigned short* __restrict__ u,
                                                float* __restrict__ out) {
  const int b = blockIdx.x;
  const int tid = threadIdx.x;
  const int lane = tid & 63, wave = tid >> 6;
  const f32x4* k4 = (const f32x4*)(key + (size_t)b * KV * DIM);
  const f32x4* v4 = (const f32x4*)(value + (size_t)b * KV * DIM);

  f32x4 qv = ((const f32x4*)(query + (size_t)b * DIM))[tid];
  ushort4 ub = ((const ushort4*)(u + (size_t)b * 2048))[tid];
  f32x4 uv;
  uv.x = bf2f(ub.x); uv.y = bf2f(ub.y); uv.z = bf2f(ub.z); uv.w = bf2f(ub.w);
  f32x4 wv = ((const f32x4*)Wa)[tid];

  float s[17];
  s[0] = dot4(qv, uv);
  float ad = dot4(qv, wv);
  #pragma unroll
  for (int j = 1; j <= 16; ++j) {
    f32x4 kv = __builtin_nontemporal_load(k4 + (j - 1) * 256 + tid);
    s[j] = dot4(uv, kv);
  }

  // prefetch all V rows BEFORE the reduction chains
  f32x4 vv[16];
  #pragma unroll
  for (int j = 0; j < 16; ++j)
    vv[j] = __builtin_nontemporal_load(v4 + j * 256 + tid);

  #pragma unroll
  for (int m = 32; m >= 1; m >>= 1) {
    #pragma unroll
    for (int j = 0; j < 17; ++j) s[j] += __shfl_xor(s[j], m);
    ad += __shfl_xor(ad, m);
  }
  __shared__ float red[4][18];
  if (lane == 0) {
    #pragma unroll
    for (int j = 0; j < 17; ++j) red[wave][j] = s[j];
    red[wave][17] = ad;
  }
  __syncthreads();

  float wt[17];
  float mx = -1e30f;
  #pragma unroll
  for (int j = 0; j < 17; ++j) {
    float t = (red[0][j] + red[1][j] + red[2][j] + red[3][j]) * 0.03125f;
    wt[j] = t;
    mx = fmaxf(mx, t);
  }
  float den = 0.f;
  #pragma unroll
  for (int j = 0; j < 17; ++j) {
    wt[j] = expf(wt[j] - mx);
    den += wt[j];
  }
  float adt = red[0][17] + red[1][17] + red[2][17] + red[3][17] + ba[0];
  float alpha = 1.0f / (1.0f + expf(-adt));
  float am = alpha / den;

  f32x4 acc = qv * wt[0];
  #pragma unroll
  for (int j = 1; j <= 16; ++j) acc += vv[j - 1] * wt[j];
  f32x4 t = qv + acc * am;

  float ssp = dot4(t, t);
  #pragma unroll
  for (int m = 32; m >= 1; m >>= 1) ssp += __shfl_xor(ssp, m);
  __shared__ float red2[4];
  if (lane == 0) red2[wave] = ssp;
  __syncthreads();
  float nrm = sqrtf(red2[0] + red2[1] + red2[2] + red2[3]);
  float inv = 1.0f / fmaxf(nrm, 1e-12f);

  __builtin_nontemporal_store(t * inv, (f32x4*)(out + (size_t)b * DIM) + tid);
}

// ---------------- launcher ----------------
extern "C" void kernel_launch(void* const* d_in, const int* in_sizes, int n_in,
                              void* d_out, int out_size, void* d_ws, size_t ws_size,
                              hipStream_t stream) {
  const float* query = (const float*)d_in[0];
  const float* key   = (const float*)d_in[1];
  const float* value = (const float*)d_in[2];
  const float* Wq    = (const float*)d_in[3];
  const float* Wk    = (const float*)d_in[4];
  const float* Wa    = (const float*)d_in[5];
  const float* ba    = (const float*)d_in[6];

  unsigned short* WqT = (unsigned short*)d_ws;              // 2 MiB
  unsigned short* WkT = WqT + (size_t)DIM * DIM;            // 2 MiB
  unsigned short* Mt  = WkT + (size_t)DIM * DIM;            // 2 MiB
  unsigned short* ubf = (unsigned short*)d_out;             // strided bf16 u inside d_out

  transpose_w<<<dim3(32, 32, 2), 256, 0, stream>>>(Wq, Wk, WqT, WkT);
  gemm_nt64ks<<<dim3(16, 16), 512, 0, stream>>>(WkT, WqT, Mt, DIM, DIM);
  gemm_u<<<512, 512, 0, stream>>>(query, Mt, ubf, DIM / 128, 2048);
  epilogue<<<BATCH, 256, 0, stream>>>(query, key, value, Wa, ba, ubf, (float*)d_out);
}